// Round 4
// baseline (13879.274 us; speedup 1.0000x reference)
//
#include <hip/hip_runtime.h>
#include <hip/hip_cooperative_groups.h>

namespace cg = cooperative_groups;

#define N 8192
#define MAX_ITER 128
#define EPS 1e-6f
#define NBLOCKS 256
#define NTHREADS 512      // 8 waves, 4 rows/wave, 32 rows/block
#define HREG 8            // float4 chunks (of 32) per row held in VGPRs: p = 0..7
// chunk p==8 held in LDS for local rows 0..30 (row 31 streams it); p = 9..31 streamed

__global__ __launch_bounds__(NTHREADS, 2)
void hop_kernel(const float* __restrict__ W,
                const float* __restrict__ bias,
                const float* __restrict__ x0,
                signed char* __restrict__ xg0,
                signed char* __restrict__ xg1,
                float* __restrict__ partial,   // [2][256] per-block energy partials
                float* __restrict__ out) {
    // LDS: wlds4 first (largest alignment), OOB row-31 slot falls into xs (harmless)
    __shared__ float4 wlds4[31 * 64];   // 31 KB: chunk p=8 for local rows 0..30
    __shared__ float  xs[N];            // 32 KB: current state, fp32
    __shared__ float  esum[8];
    __shared__ float  ebc;

    cg::grid_group grid = cg::this_grid();

    const int tid  = threadIdx.x;
    const int wave = tid >> 6;
    const int lane = tid & 63;
    const int bid  = blockIdx.x;
    const int rowBase = (bid << 5) + (wave << 2);
    const int rl = wave << 2;           // local row index of r=0

    const float4* Wr0 = (const float4*)(W + (size_t)(rowBase + 0) * N);
    const float4* Wr1 = (const float4*)(W + (size_t)(rowBase + 1) * N);
    const float4* Wr2 = (const float4*)(W + (size_t)(rowBase + 2) * N);
    const float4* Wr3 = (const float4*)(W + (size_t)(rowBase + 3) * N);
    const float4* xs4 = (const float4*)xs;

    // ---- prologue: pin held W chunks in VGPRs + LDS, load bias, stage x0 ----
    float4 wreg[4][HREG];
    #pragma unroll
    for (int p = 0; p < HREG; ++p) {
        const int o = (p << 6) + lane;
        wreg[0][p] = Wr0[o]; wreg[1][p] = Wr1[o];
        wreg[2][p] = Wr2[o]; wreg[3][p] = Wr3[o];
    }
    {
        const int o = (HREG << 6) + lane;
        wlds4[(rl + 0) * 64 + lane] = Wr0[o];
        wlds4[(rl + 1) * 64 + lane] = Wr1[o];
        wlds4[(rl + 2) * 64 + lane] = Wr2[o];
        if (wave != 7) wlds4[(rl + 3) * 64 + lane] = Wr3[o];  // row 31 streams p=8
    }
    float breg[4] = {0.f, 0.f, 0.f, 0.f};
    if (lane == 0) {
        breg[0] = bias[rowBase + 0]; breg[1] = bias[rowBase + 1];
        breg[2] = bias[rowBase + 2]; breg[3] = bias[rowBase + 3];
    }
    {
        const float4* x04 = (const float4*)x0;
        float4* s4 = (float4*)xs;
        #pragma unroll
        for (int k = 0; k < 4; ++k) s4[tid + (k << 9)] = x04[tid + (k << 9)];
    }
    __syncthreads();

    float e1 = 0.f, e2 = 0.f;   // E_{t-1}, E_{t-2}
    int finBuf = -1;

    for (int t = 0; t < MAX_ITER; ++t) {
        if (t >= 1) {
            // E_{t-1}: deterministic fixed-order sum of 256 block partials
            if (wave == 0) {
                const float4* p4 = (const float4*)(partial + ((t - 1) & 1) * 256);
                float4 pv = p4[lane];
                float s = (pv.x + pv.y) + (pv.z + pv.w);
                #pragma unroll
                for (int off = 32; off; off >>= 1) s += __shfl_down(s, off);
                if (lane == 0) ebc = s;
            }
            // restage x_t from packed bytes (written by iter t-1, grid-synced)
            const signed char* xin = (t & 1) ? xg1 : xg0;
            #pragma unroll
            for (int k = 0; k < 16; ++k) {
                const int e = tid + (k << 9);
                xs[e] = (float)xin[e];
            }
            __syncthreads();
            e2 = e1; e1 = ebc;
            if (t >= 2 && fabsf(e1 - e2) < EPS) {
                finBuf = (t - 1) & 1;   // final x = x_{t-1}, intact (double buffer)
                break;                  // uniform across grid: same e1,e2 everywhere
            }
        }

        // ---- 4-row matvec; accumulation order bitwise-matches R3 kernel ----
        float acc[4][4] = {{0,0,0,0},{0,0,0,0},{0,0,0,0},{0,0,0,0}};
        #pragma unroll
        for (int pp = 0; pp < 8; ++pp) {
            #pragma unroll
            for (int i = 0; i < 4; ++i) {
                const int p = (pp << 2) + i;      // acc[r][i] sums p ≡ i (mod 4), ascending
                const int o = (p << 6) + lane;
                const float4 q = xs4[o];
                #pragma unroll
                for (int r = 0; r < 4; ++r) {
                    float4 w;
                    if (p < HREG) {
                        w = wreg[r][p];
                    } else if (p == HREG) {
                        if (r == 3 && wave == 7) w = Wr3[o];           // row 31 streams
                        else                     w = wlds4[(rl + r) * 64 + lane];
                    } else {
                        w = (r == 0) ? Wr0[o] : (r == 1) ? Wr1[o]
                          : (r == 2) ? Wr2[o] : Wr3[o];
                    }
                    acc[r][i] += w.x * q.x + w.y * q.y + w.z * q.z + w.w * q.w;
                }
            }
        }

        signed char* xout = ((t + 1) & 1) ? xg1 : xg0;
        float tot[4];
        #pragma unroll
        for (int r = 0; r < 4; ++r) {
            float s = (acc[r][0] + acc[r][1]) + (acc[r][2] + acc[r][3]);
            #pragma unroll
            for (int off = 32; off; off >>= 1) s += __shfl_down(s, off);
            tot[r] = s;   // valid on lane 0
        }
        if (lane == 0) {
            float ew = 0.f;
            #pragma unroll
            for (int r = 0; r < 4; ++r) {
                const float v = tot[r] + breg[r];
                xout[rowBase + r] = (signed char)((v > 0.f) ? 1 : ((v < 0.f) ? -1 : 0));
                const float xr = xs[rowBase + r];
                ew += -0.5f * xr * tot[r] - breg[r] * xr;
            }
            esum[wave] = ew;
        }
        __syncthreads();
        if (tid == 0) {
            float bp = 0.f;
            #pragma unroll
            for (int w = 0; w < 8; ++w) bp += esum[w];
            partial[(t & 1) * 256 + bid] = bp;
        }
        grid.sync();   // publishes xout + partial[t&1] device-wide
    }

    if (finBuf < 0) {
        // loop completed: decide between x_127 (k=127 converged) and x_128
        if (wave == 0) {
            const float4* p4 = (const float4*)(partial + 256);  // t=127 partials
            float4 pv = p4[lane];
            float s = (pv.x + pv.y) + (pv.z + pv.w);
            #pragma unroll
            for (int off = 32; off; off >>= 1) s += __shfl_down(s, off);
            if (lane == 0) ebc = s;
        }
        __syncthreads();
        const float e127 = ebc;            // e1 == E_126 here
        finBuf = (fabsf(e127 - e1) < EPS) ? 1 : 0;   // x_127 in xg1, x_128 in xg0
    }
    const signed char* xf = finBuf ? xg1 : xg0;
    if (tid < 32) {
        const int i = (bid << 5) + tid;
        out[i] = (float)xf[i];
    }
}

extern "C" void kernel_launch(void* const* d_in, const int* in_sizes, int n_in,
                              void* d_out, int out_size, void* d_ws, size_t ws_size,
                              hipStream_t stream) {
    const float* x0 = (const float*)d_in[0];   // (8192,)
    const float* W  = (const float*)d_in[1];   // (8192, 8192)
    const float* b  = (const float*)d_in[2];   // (8192,)
    float* out = (float*)d_out;

    float*       partial = (float*)d_ws;                  // [2][256]
    signed char* xg0     = (signed char*)(partial + 512); // [N] packed state ping
    signed char* xg1     = xg0 + N;                       // [N] packed state pong

    void* args[] = { (void*)&W, (void*)&b, (void*)&x0,
                     (void*)&xg0, (void*)&xg1, (void*)&partial, (void*)&out };
    hipLaunchCooperativeKernel((const void*)hop_kernel, dim3(NBLOCKS), dim3(NTHREADS),
                               args, 0, stream);
}

// Round 5
// 4827.638 us; speedup vs baseline: 2.8750x; 2.8750x over previous
//
#include <hip/hip_runtime.h>
#include <hip/hip_fp16.h>

#define N 8192
#define MAX_ITER 128
#define EPS 1e-6f
#define TAU 0.25f          // fp16 row-sum error sigma ~0.01 -> 25-sigma guard band
#define LISTCAP 1024

__device__ __forceinline__ float sgnf(float v) {
    return (v > 0.f) ? 1.f : ((v < 0.f) ? -1.f : 0.f);
}
__device__ __forceinline__ float2 h2pair(unsigned u) {
    union { unsigned u; __half2 h; } c; c.u = u;
    return __half22float2(c.h);
}
__device__ __forceinline__ unsigned pair2h(float a, float b) {
    union { __half2 h; unsigned u; } c; c.h = __floats2half2_rn(a, b);
    return c.u;
}

// ---------------------------------------------------------------------------
// compress: W fp32 -> fp16 (RNE). 8 elts/thread.
// ---------------------------------------------------------------------------
__global__ __launch_bounds__(256) void compress_kernel(const float* __restrict__ W,
                                                       unsigned short* __restrict__ Wh) {
    size_t base = ((size_t)blockIdx.x * 256 + threadIdx.x) * 8;
    const float4* w4 = (const float4*)(W + base);
    float4 a = w4[0], b = w4[1];
    uint4 o;
    o.x = pair2h(a.x, a.y); o.y = pair2h(a.z, a.w);
    o.z = pair2h(b.x, b.y); o.w = pair2h(b.z, b.w);
    *(uint4*)(Wh + base) = o;
}

__global__ __launch_bounds__(256) void init_kernel(float* __restrict__ eacc,
                                                   int* __restrict__ cnt,
                                                   int* __restrict__ done) {
    int i = threadIdx.x;
    if (i < MAX_ITER) { eacc[i] = 0.f; cnt[i] = 0; }
    if (i == 0) *done = 0;
}

// ---------------------------------------------------------------------------
// passA(t): stage x_t (t==0 from x0; else sign(y_{t-1}+b)) into LDS as fp16,
// compute E_{t-1} deterministically (identical in every block), convergence
// check, then fp16 screening matvec y_t; rows with |v+b|<TAU -> list.
// ---------------------------------------------------------------------------
__global__ __launch_bounds__(512, 4)
void passA(const unsigned short* __restrict__ Wh,
           const float* __restrict__ bias,
           const float* __restrict__ x0,
           const float* __restrict__ yin,      // y_{t-1} (corrected)
           float* __restrict__ yout,           // y_t
           const signed char* __restrict__ xprev,  // packed x_{t-1} (t>=2)
           signed char* __restrict__ xout,         // packed x_t (block 0 writes)
           float* __restrict__ eacc,
           int* __restrict__ cnt,
           int* __restrict__ rows,
           int t,
           int* __restrict__ done) {
    if (*done) return;                       // uniform

    __shared__ unsigned short xs_h[N];       // 16 KB: x_t as packed fp16
    __shared__ float red[512];

    const int tid = threadIdx.x;
    float epart = 0.f;

    if (t == 0) {
        const float4* x4 = (const float4*)x0;
        for (int i = tid; i < N / 4; i += 512) {
            float4 v = x4[i];
            ((uint2*)xs_h)[i] = make_uint2(pair2h(v.x, v.y), pair2h(v.z, v.w));
        }
    } else {
        const float4* y4 = (const float4*)yin;
        const float4* b4 = (const float4*)bias;
        const char4*  xp4 = (const char4*)xprev;
        const float4* x04 = (const float4*)x0;
        const bool wr = (blockIdx.x == 0);
        for (int i = tid; i < N / 4; i += 512) {
            float4 y = y4[i];
            float4 b = b4[i];
            // energy of x_{t-1}: sum x_{t-1,r} * (-0.5*y_r - b_r)
            float4 xp;
            if (t == 1) { xp = x04[i]; }
            else { char4 c = xp4[i]; xp = make_float4((float)c.x, (float)c.y,
                                                     (float)c.z, (float)c.w); }
            epart += ((xp.x * (-0.5f * y.x - b.x) + xp.y * (-0.5f * y.y - b.y)) +
                      (xp.z * (-0.5f * y.z - b.z) + xp.w * (-0.5f * y.w - b.w)));
            // x_t = sign(y + b)
            float s0 = sgnf(y.x + b.x), s1 = sgnf(y.y + b.y);
            float s2 = sgnf(y.z + b.z), s3 = sgnf(y.w + b.w);
            ((uint2*)xs_h)[i] = make_uint2(pair2h(s0, s1), pair2h(s2, s3));
            if (wr) ((char4*)xout)[i] = make_char4((signed char)s0, (signed char)s1,
                                                   (signed char)s2, (signed char)s3);
        }
    }

    // deterministic block reduction of epart (identical value in all blocks)
    red[tid] = epart;
    __syncthreads();
    #pragma unroll
    for (int s = 256; s > 0; s >>= 1) {
        if (tid < s) red[tid] += red[tid + s];
        __syncthreads();
    }
    const float E = red[0];                  // E_{t-1} (garbage for t==0, unused)

    if (t >= 2) {
        if (fabsf(E - eacc[t - 2]) < EPS) {  // uniform across grid
            if (tid == 0 && blockIdx.x == 0) *done = 1 + ((t - 1) & 1);
            return;                          // final = x_{t-1} in xpk[(t-1)&1]
        }
    }
    if (t >= 1 && blockIdx.x == 0 && tid == 0) eacc[t - 1] = E;

    // ---- fp16 screening matvec: 1 row/wave ----
    const int wave = tid >> 6;
    const int lane = tid & 63;
    const int row  = ((int)blockIdx.x << 3) + wave;

    const uint4* Wr = (const uint4*)(Wh + (size_t)row * N);  // 1024 uint4/row
    const uint4* Xr = (const uint4*)xs_h;

    float a0 = 0.f, a1 = 0.f, a2 = 0.f, a3 = 0.f;
    #pragma unroll
    for (int p = 0; p < 16; ++p) {
        const int j = (p << 6) + lane;
        uint4 wq = Wr[j];
        uint4 xq = Xr[j];
        float2 w0 = h2pair(wq.x), q0 = h2pair(xq.x);
        float2 w1 = h2pair(wq.y), q1 = h2pair(xq.y);
        float2 w2 = h2pair(wq.z), q2 = h2pair(xq.z);
        float2 w3 = h2pair(wq.w), q3 = h2pair(xq.w);
        a0 += w0.x * q0.x + w0.y * q0.y;
        a1 += w1.x * q1.x + w1.y * q1.y;
        a2 += w2.x * q2.x + w2.y * q2.y;
        a3 += w3.x * q3.x + w3.y * q3.y;
    }
    float tot = (a0 + a1) + (a2 + a3);
    #pragma unroll
    for (int off = 32; off > 0; off >>= 1) tot += __shfl_down(tot, off);

    if (lane == 0) {
        yout[row] = tot;
        float u = tot + bias[row];
        if (fabsf(u) < TAU) {                // uncertain: queue fp32 recompute
            int k = atomicAdd(&cnt[t], 1);
            if (k < LISTCAP) rows[t * LISTCAP + k] = row;
        }
    }
}

// ---------------------------------------------------------------------------
// passB(t): fp32 recompute of uncertain rows, bitwise-identical to the R3
// (validated absmax=0) accumulation order. Overwrites yout[row].
// ---------------------------------------------------------------------------
__global__ __launch_bounds__(512)
void passB(const float* __restrict__ W,
           const float* __restrict__ x0,
           const signed char* __restrict__ xin,   // packed x_t (t>=1)
           float* __restrict__ yout,
           const int* __restrict__ cnt,
           const int* __restrict__ rows,
           int t,
           const int* __restrict__ done) {
    if (*done) return;

    __shared__ float xs[N];                  // 32 KB, fp32 — exact R3 staging
    if (t == 0) {
        const float4* x4 = (const float4*)x0;
        float4* s4 = (float4*)xs;
        for (int i = threadIdx.x; i < N / 4; i += 512) s4[i] = x4[i];
    } else {
        #pragma unroll
        for (int k = 0; k < 16; ++k) {
            const int e = threadIdx.x + (k << 9);
            xs[e] = (float)xin[e];
        }
    }
    __syncthreads();

    int n = cnt[t];
    if (n > LISTCAP) n = LISTCAP;
    const int lane   = threadIdx.x & 63;
    const int waveId = ((int)blockIdx.x << 3) + (threadIdx.x >> 6);
    const int nwaves = (int)gridDim.x << 3;
    const float4* xs4 = (const float4*)xs;

    for (int i = waveId; i < n; i += nwaves) {
        const int row = rows[t * LISTCAP + i];
        const float4* Wr = (const float4*)(W + (size_t)row * N);
        float a0 = 0.f, a1 = 0.f, a2 = 0.f, a3 = 0.f;
        #pragma unroll
        for (int p = 0; p < 8; ++p) {        // EXACT R3 inner body
            int j = p * 256 + lane;
            float4 w0 = Wr[j];         float4 q0 = xs4[j];
            float4 w1 = Wr[j + 64];    float4 q1 = xs4[j + 64];
            float4 w2 = Wr[j + 128];   float4 q2 = xs4[j + 128];
            float4 w3 = Wr[j + 192];   float4 q3 = xs4[j + 192];
            a0 += w0.x * q0.x + w0.y * q0.y + w0.z * q0.z + w0.w * q0.w;
            a1 += w1.x * q1.x + w1.y * q1.y + w1.z * q1.z + w1.w * q1.w;
            a2 += w2.x * q2.x + w2.y * q2.y + w2.z * q2.z + w2.w * q2.w;
            a3 += w3.x * q3.x + w3.y * q3.y + w3.z * q3.z + w3.w * q3.w;
        }
        float tot = (a0 + a1) + (a2 + a3);
        #pragma unroll
        for (int off = 32; off > 0; off >>= 1) tot += __shfl_down(tot, off);
        if (lane == 0) yout[row] = tot;
    }
}

// ---------------------------------------------------------------------------
// out: if done -> decode frozen xpk; else do the k=127 check (E_127 vs E_126)
// and emit x_127 or x_128 = sign(y_127 + b). Single block, deterministic.
// ---------------------------------------------------------------------------
__global__ __launch_bounds__(512)
void out_kernel(const float* __restrict__ bias,
                const signed char* __restrict__ xpk0,
                const signed char* __restrict__ xpk1,
                const float* __restrict__ y127,     // yv[1]
                const float* __restrict__ eacc,
                const int* __restrict__ done,
                float* __restrict__ out) {
    __shared__ float red[512];
    const int tid = threadIdx.x;
    const int d = *done;
    float4* o4 = (float4*)out;

    if (d) {
        const char4* p4 = (const char4*)((d - 1) ? xpk1 : xpk0);
        for (int i = tid; i < N / 4; i += 512) {
            char4 c = p4[i];
            o4[i] = make_float4((float)c.x, (float)c.y, (float)c.z, (float)c.w);
        }
        return;
    }
    const char4*  xp4 = (const char4*)xpk1;      // x_127
    const float4* y4  = (const float4*)y127;
    const float4* b4  = (const float4*)bias;
    float ep = 0.f;
    for (int i = tid; i < N / 4; i += 512) {
        char4 c = xp4[i];
        float4 y = y4[i], b = b4[i];
        ep += (((float)c.x * (-0.5f * y.x - b.x) + (float)c.y * (-0.5f * y.y - b.y)) +
               ((float)c.z * (-0.5f * y.z - b.z) + (float)c.w * (-0.5f * y.w - b.w)));
    }
    red[tid] = ep;
    __syncthreads();
    #pragma unroll
    for (int s = 256; s > 0; s >>= 1) {
        if (tid < s) red[tid] += red[tid + s];
        __syncthreads();
    }
    const bool conv = fabsf(red[0] - eacc[126]) < EPS;  // k=127 check
    for (int i = tid; i < N / 4; i += 512) {
        char4 c = xp4[i];
        float4 y = y4[i], b = b4[i];
        float4 r;
        r.x = conv ? (float)c.x : sgnf(y.x + b.x);
        r.y = conv ? (float)c.y : sgnf(y.y + b.y);
        r.z = conv ? (float)c.z : sgnf(y.z + b.z);
        r.w = conv ? (float)c.w : sgnf(y.w + b.w);
        o4[i] = r;
    }
}

// ===========================================================================
// Fallback (ws too small): the validated R3 full-fp32 chain.
// ===========================================================================
__global__ __launch_bounds__(256) void fb_init(float* __restrict__ eacc,
                                               int* __restrict__ done) {
    int i = threadIdx.x;
    if (i <= MAX_ITER) eacc[i] = 0.0f;
    if (i == 0) *done = 0;
}

__global__ __launch_bounds__(512, 4) void fb_mv(const float* __restrict__ W,
                                                const float* __restrict__ bias,
                                                const float* __restrict__ x0,
                                                const signed char* __restrict__ xin,
                                                signed char* __restrict__ xnext,
                                                float* __restrict__ eacc,
                                                int t,
                                                int* __restrict__ done) {
    if (t >= 2) {
        if (*done) return;
        float d = fabsf(eacc[t - 1] - eacc[t - 2]);
        if (d < EPS) {
            if (threadIdx.x == 0) *done = 1 + ((t - 1) & 1);
            return;
        }
    }
    __shared__ float xs[N];
    __shared__ float wsum[8];
    if (t == 0) {
        const float4* x4 = (const float4*)x0;
        float4* s4 = (float4*)xs;
        for (int i = threadIdx.x; i < N / 4; i += 512) s4[i] = x4[i];
    } else {
        #pragma unroll
        for (int k = 0; k < 16; ++k) {
            int e = threadIdx.x + k * 512;
            xs[e] = (float)xin[e];
        }
    }
    __syncthreads();
    const int wave = threadIdx.x >> 6;
    const int lane = threadIdx.x & 63;
    const int row  = ((int)blockIdx.x << 3) + wave;
    const float4* Wr  = (const float4*)(W + (size_t)row * N);
    const float4* xs4 = (const float4*)xs;
    float a0 = 0.f, a1 = 0.f, a2 = 0.f, a3 = 0.f;
    #pragma unroll
    for (int p = 0; p < 8; ++p) {
        int j = p * 256 + lane;
        float4 w0 = Wr[j];         float4 q0 = xs4[j];
        float4 w1 = Wr[j + 64];    float4 q1 = xs4[j + 64];
        float4 w2 = Wr[j + 128];   float4 q2 = xs4[j + 128];
        float4 w3 = Wr[j + 192];   float4 q3 = xs4[j + 192];
        a0 += w0.x * q0.x + w0.y * q0.y + w0.z * q0.z + w0.w * q0.w;
        a1 += w1.x * q1.x + w1.y * q1.y + w1.z * q1.z + w1.w * q1.w;
        a2 += w2.x * q2.x + w2.y * q2.y + w2.z * q2.z + w2.w * q2.w;
        a3 += w3.x * q3.x + w3.y * q3.y + w3.z * q3.z + w3.w * q3.w;
    }
    float tot = (a0 + a1) + (a2 + a3);
    #pragma unroll
    for (int off = 32; off > 0; off >>= 1) tot += __shfl_down(tot, off);
    if (lane == 0) {
        float br = bias[row];
        float v = tot + br;
        xnext[row] = (signed char)((v > 0.f) ? 1 : ((v < 0.f) ? -1 : 0));
        float xr = xs[row];
        wsum[wave] = -0.5f * xr * tot - br * xr;
    }
    __syncthreads();
    if (threadIdx.x == 0) {
        float s = 0.f;
        #pragma unroll
        for (int w = 0; w < 8; ++w) s += wsum[w];
        atomicAdd(&eacc[t], s);
    }
}

__global__ __launch_bounds__(256) void fb_out(const signed char* __restrict__ p0,
                                              const signed char* __restrict__ p1,
                                              const int* __restrict__ done,
                                              float* __restrict__ out) {
    int i = blockIdx.x * 256 + threadIdx.x;
    int d = *done;
    const signed char* p = d ? ((d - 1) ? p1 : p0) : p0;
    out[i] = (float)p[i];
}

// ===========================================================================
extern "C" void kernel_launch(void* const* d_in, const int* in_sizes, int n_in,
                              void* d_out, int out_size, void* d_ws, size_t ws_size,
                              hipStream_t stream) {
    const float* x0 = (const float*)d_in[0];   // (8192,)
    const float* W  = (const float*)d_in[1];   // (8192, 8192) fp32
    const float* b  = (const float*)d_in[2];   // (8192,)
    float* out = (float*)d_out;

    // fast-path workspace layout
    char* p = (char*)d_ws;
    unsigned short* Wh = (unsigned short*)p;  p += (size_t)N * N * 2;  // 128 MiB
    float* yv   = (float*)p;                  p += 2 * N * sizeof(float);
    signed char* xpk = (signed char*)p;       p += 2 * N;
    float* eacc = (float*)p;                  p += MAX_ITER * sizeof(float);
    int*   cnt  = (int*)p;                    p += MAX_ITER * sizeof(int);
    int*   rows = (int*)p;                    p += MAX_ITER * LISTCAP * sizeof(int);
    int*   done = (int*)p;                    p += 16;
    const size_t needed = (size_t)(p - (char*)d_ws);

    if (ws_size >= needed) {
        compress_kernel<<<(int)((size_t)N * N / (256 * 8)), 256, 0, stream>>>(W, Wh);
        init_kernel<<<1, 256, 0, stream>>>(eacc, cnt, done);
        for (int t = 0; t < MAX_ITER; ++t) {
            const float* yin = yv + ((t + 1) & 1) * N;          // y_{t-1}
            float*      yout = yv + (t & 1) * N;                // y_t
            const signed char* xprev = xpk + ((t + 1) & 1) * N; // x_{t-1}
            signed char*       xout  = xpk + (t & 1) * N;       // x_t
            passA<<<N / 8, 512, 0, stream>>>(Wh, b, x0, yin, yout, xprev, xout,
                                             eacc, cnt, rows, t, done);
            passB<<<64, 512, 0, stream>>>(W, x0, xout, yout, cnt, rows, t, done);
        }
        out_kernel<<<1, 512, 0, stream>>>(b, xpk, xpk + N, yv + N, eacc, done, out);
    } else {
        // fallback: validated R3 chain
        float*       feacc = (float*)d_ws;
        int*         fdone = (int*)(feacc + MAX_ITER + 2);
        signed char* p0    = (signed char*)(fdone + 16);
        signed char* p1    = p0 + N;
        fb_init<<<1, 256, 0, stream>>>(feacc, fdone);
        for (int t = 0; t <= MAX_ITER; ++t) {
            const signed char* xin   = (t & 1) ? p1 : p0;
            signed char*       xnext = (t & 1) ? p0 : p1;
            fb_mv<<<N / 8, 512, 0, stream>>>(W, b, x0, xin, xnext, feacc, t, fdone);
        }
        fb_out<<<N / 256, 256, 0, stream>>>(p0, p1, fdone, out);
    }
}

// Round 6
// 4611.305 us; speedup vs baseline: 3.0098x; 1.0469x over previous
//
#include <hip/hip_runtime.h>

#define N 8192
#define MAX_ITER 128
#define EPS 1e-6f
#define TAU_I8 12.0f     // int8 row-sum quant noise sigma ~1.63 -> 7.3-sigma band
#define LISTCAP 2048     // expected ~865 flagged rows/iter; 2048 = +40 sigma
#define QSCALE 16.0f
#define QINV 0.0625f

__device__ __forceinline__ float sgnf(float v) {
    return (v > 0.f) ? 1.f : ((v < 0.f) ? -1.f : 0.f);
}

// ---------------------------------------------------------------------------
// init: zero eacc/cnt/done/satflag (ws is re-poisoned 0xAA before every call)
// ---------------------------------------------------------------------------
__global__ __launch_bounds__(256) void init_kernel(float* __restrict__ eacc,
                                                   int* __restrict__ cnt,
                                                   int* __restrict__ done,
                                                   int* __restrict__ satflag) {
    int i = blockIdx.x * 256 + threadIdx.x;
    if (i < N) satflag[i] = 0;
    if (i < MAX_ITER) { eacc[i] = 0.f; cnt[i] = 0; }
    if (i == 0) *done = 0;
}

// ---------------------------------------------------------------------------
// compress: W fp32 -> int8 (RNE, scale 16). 16 elts/thread. Saturation (never
// happens for N(0,1) data) marks the row for mandatory exact recompute.
// ---------------------------------------------------------------------------
__global__ __launch_bounds__(256) void compress_kernel(const float* __restrict__ W,
                                                       signed char* __restrict__ Wq,
                                                       int* __restrict__ satflag) {
    const size_t base = ((size_t)blockIdx.x * 256 + threadIdx.x) * 16;
    const float4* w4 = (const float4*)(W + base);
    float4 v0 = w4[0], v1 = w4[1], v2 = w4[2], v3 = w4[3];
    int sat = 0;
    auto q1 = [&](float x) -> unsigned {
        int q = __float2int_rn(x * QSCALE);
        if (q > 127)  { q = 127;  sat = 1; }
        if (q < -127) { q = -127; sat = 1; }
        return (unsigned)(q & 0xff);
    };
    uint4 o;
    o.x = q1(v0.x) | (q1(v0.y) << 8) | (q1(v0.z) << 16) | (q1(v0.w) << 24);
    o.y = q1(v1.x) | (q1(v1.y) << 8) | (q1(v1.z) << 16) | (q1(v1.w) << 24);
    o.z = q1(v2.x) | (q1(v2.y) << 8) | (q1(v2.z) << 16) | (q1(v2.w) << 24);
    o.w = q1(v3.x) | (q1(v3.y) << 8) | (q1(v3.z) << 16) | (q1(v3.w) << 24);
    *(uint4*)(Wq + base) = o;
    if (sat) atomicOr(&satflag[base >> 13], 1);
}

// ---------------------------------------------------------------------------
// passA(t): int8 screening matvec.
//   - each wave preloads its full 8KB int8 W row into 32 VGPRs (HBM busy at t=0)
//   - stage x_t (t==0: x0; else sign(yin+b)) into 4 padded LDS planes
//   - deterministic per-block energy E_{t-1}, convergence check
//   - screen: tot exact-integer fp32; |tot/16 + b| < TAU -> row to exact list
// ---------------------------------------------------------------------------
__global__ __launch_bounds__(512, 4)
void passA(const signed char* __restrict__ Wq,
           const float* __restrict__ bias,
           const float* __restrict__ x0,
           const float* __restrict__ yin,      // y_{t-1} (passB-corrected)
           float* __restrict__ yout,           // y_t (screen values)
           const signed char* __restrict__ xprev,  // packed x_{t-1} (t>=2)
           signed char* __restrict__ xout,         // packed x_t (block 0 writes)
           float* __restrict__ eacc,
           int* __restrict__ cnt,
           int* __restrict__ rows,
           const int* __restrict__ satflag,
           int t,
           int* __restrict__ done) {
    if (*done) return;                       // uniform

    __shared__ float xsw[4 * 2052];          // 4 planes x 513 float4 (pad kills conflicts)
    __shared__ float red[512];

    const int tid  = threadIdx.x;
    const int wave = tid >> 6;
    const int lane = tid & 63;
    const int row  = ((int)blockIdx.x << 3) + wave;

    // ---- preload entire int8 row into registers ----
    const uint4* Wr = (const uint4*)(Wq + (size_t)row * N);   // 512 uint4/row
    uint4 wq[8];
    #pragma unroll
    for (int p = 0; p < 8; ++p) wq[p] = Wr[(p << 6) + lane];

    float4* xsw4 = (float4*)xsw;
    float epart = 0.f;

    if (t == 0) {
        const float4* x4 = (const float4*)x0;
        for (int i = tid; i < N / 4; i += 512)
            xsw4[(i & 3) * 513 + (i >> 2)] = x4[i];
    } else {
        const float4* y4  = (const float4*)yin;
        const float4* b4  = (const float4*)bias;
        const char4*  xp4 = (const char4*)xprev;
        const float4* x04 = (const float4*)x0;
        const bool wr = (blockIdx.x == 0);
        for (int i = tid; i < N / 4; i += 512) {
            float4 y = y4[i];
            float4 b = b4[i];
            float4 xp;                        // x_{t-1} for energy
            if (t == 1) { xp = x04[i]; }
            else { char4 c = xp4[i]; xp = make_float4((float)c.x, (float)c.y,
                                                      (float)c.z, (float)c.w); }
            epart += ((xp.x * (-0.5f * y.x - b.x) + xp.y * (-0.5f * y.y - b.y)) +
                      (xp.z * (-0.5f * y.z - b.z) + xp.w * (-0.5f * y.w - b.w)));
            float4 s;
            s.x = sgnf(y.x + b.x); s.y = sgnf(y.y + b.y);
            s.z = sgnf(y.z + b.z); s.w = sgnf(y.w + b.w);
            xsw4[(i & 3) * 513 + (i >> 2)] = s;
            if (wr) ((char4*)xout)[i] = make_char4((signed char)s.x, (signed char)s.y,
                                                   (signed char)s.z, (signed char)s.w);
        }
    }

    // deterministic block reduction (identical E in every block)
    red[tid] = epart;
    __syncthreads();
    #pragma unroll
    for (int s = 256; s > 0; s >>= 1) {
        if (tid < s) red[tid] += red[tid + s];
        __syncthreads();
    }
    const float E = red[0];                  // E_{t-1} (unused for t==0)

    if (t >= 2 && fabsf(E - eacc[t - 2]) < EPS) {   // uniform across grid
        if (tid == 0 && blockIdx.x == 0) *done = 1 + ((t - 1) & 1);
        return;                              // final = x_{t-1}, frozen in xpk
    }
    if (t >= 1 && blockIdx.x == 0 && tid == 0) eacc[t - 1] = E;

    // ---- int8 dot: exact integer accumulation in fp32 ----
    float a0 = 0.f, a1 = 0.f, a2 = 0.f, a3 = 0.f;
    #pragma unroll
    for (int p = 0; p < 8; ++p) {
        const int j = (p << 6) + lane;
        const float4 q0 = xsw4[j];           // elements 16j+0 .. 16j+3
        const float4 q1 = xsw4[513 + j];     // 16j+4 .. 16j+7
        const float4 q2 = xsw4[1026 + j];    // 16j+8 .. 16j+11
        const float4 q3 = xsw4[1539 + j];    // 16j+12 .. 16j+15
        const uint4 w = wq[p];
        a0 += (float)(signed char)(w.x & 0xff)         * q0.x
            + (float)(signed char)((w.x >> 8) & 0xff)  * q0.y
            + (float)(signed char)((w.x >> 16) & 0xff) * q0.z
            + (float)(signed char)(w.x >> 24)          * q0.w;
        a1 += (float)(signed char)(w.y & 0xff)         * q1.x
            + (float)(signed char)((w.y >> 8) & 0xff)  * q1.y
            + (float)(signed char)((w.y >> 16) & 0xff) * q1.z
            + (float)(signed char)(w.y >> 24)          * q1.w;
        a2 += (float)(signed char)(w.z & 0xff)         * q2.x
            + (float)(signed char)((w.z >> 8) & 0xff)  * q2.y
            + (float)(signed char)((w.z >> 16) & 0xff) * q2.z
            + (float)(signed char)(w.z >> 24)          * q2.w;
        a3 += (float)(signed char)(w.w & 0xff)         * q3.x
            + (float)(signed char)((w.w >> 8) & 0xff)  * q3.y
            + (float)(signed char)((w.w >> 16) & 0xff) * q3.z
            + (float)(signed char)(w.w >> 24)          * q3.w;
    }
    float tot = (a0 + a1) + (a2 + a3);
    #pragma unroll
    for (int off = 32; off > 0; off >>= 1) tot += __shfl_down(tot, off);

    if (lane == 0) {
        const float ys = tot * QINV;
        yout[row] = ys;
        const float u = ys + bias[row];
        if (fabsf(u) < TAU_I8 || satflag[row]) {
            int k = atomicAdd(&cnt[t], 1);
            if (k < LISTCAP) rows[t * LISTCAP + k] = row;
        }
    }
}

// ---------------------------------------------------------------------------
// passB(t): fp32 recompute of uncertain rows, bitwise-identical to the R3
// (validated absmax=0) accumulation order. Overwrites yout[row].
// ---------------------------------------------------------------------------
__global__ __launch_bounds__(512)
void passB(const float* __restrict__ W,
           const float* __restrict__ x0,
           const signed char* __restrict__ xin,   // packed x_t (t>=1)
           float* __restrict__ yout,
           const int* __restrict__ cnt,
           const int* __restrict__ rows,
           int t,
           const int* __restrict__ done) {
    if (*done) return;

    __shared__ float xs[N];                  // 32 KB, fp32 — exact R3 staging
    if (t == 0) {
        const float4* x4 = (const float4*)x0;
        float4* s4 = (float4*)xs;
        for (int i = threadIdx.x; i < N / 4; i += 512) s4[i] = x4[i];
    } else {
        #pragma unroll
        for (int k = 0; k < 16; ++k) {
            const int e = threadIdx.x + (k << 9);
            xs[e] = (float)xin[e];
        }
    }
    __syncthreads();

    int n = cnt[t];
    if (n > LISTCAP) n = LISTCAP;
    const int lane   = threadIdx.x & 63;
    const int waveId = ((int)blockIdx.x << 3) + (threadIdx.x >> 6);
    const int nwaves = (int)gridDim.x << 3;
    const float4* xs4 = (const float4*)xs;

    for (int i = waveId; i < n; i += nwaves) {
        const int row = rows[t * LISTCAP + i];
        const float4* Wr = (const float4*)(W + (size_t)row * N);
        float a0 = 0.f, a1 = 0.f, a2 = 0.f, a3 = 0.f;
        #pragma unroll
        for (int p = 0; p < 8; ++p) {        // EXACT R3 inner body
            int j = p * 256 + lane;
            float4 w0 = Wr[j];         float4 q0 = xs4[j];
            float4 w1 = Wr[j + 64];    float4 q1 = xs4[j + 64];
            float4 w2 = Wr[j + 128];   float4 q2 = xs4[j + 128];
            float4 w3 = Wr[j + 192];   float4 q3 = xs4[j + 192];
            a0 += w0.x * q0.x + w0.y * q0.y + w0.z * q0.z + w0.w * q0.w;
            a1 += w1.x * q1.x + w1.y * q1.y + w1.z * q1.z + w1.w * q1.w;
            a2 += w2.x * q2.x + w2.y * q2.y + w2.z * q2.z + w2.w * q2.w;
            a3 += w3.x * q3.x + w3.y * q3.y + w3.z * q3.z + w3.w * q3.w;
        }
        float tot = (a0 + a1) + (a2 + a3);
        #pragma unroll
        for (int off = 32; off > 0; off >>= 1) tot += __shfl_down(tot, off);
        if (lane == 0) yout[row] = tot;
    }
}

// ---------------------------------------------------------------------------
// out: if done -> decode frozen xpk; else do the k=127 check (E_127 vs E_126)
// and emit x_127 or x_128 = sign(y_127 + b). Single block, deterministic.
// ---------------------------------------------------------------------------
__global__ __launch_bounds__(512)
void out_kernel(const float* __restrict__ bias,
                const signed char* __restrict__ xpk0,
                const signed char* __restrict__ xpk1,
                const float* __restrict__ y127,     // yv[1]
                const float* __restrict__ eacc,
                const int* __restrict__ done,
                float* __restrict__ out) {
    __shared__ float red[512];
    const int tid = threadIdx.x;
    const int d = *done;
    float4* o4 = (float4*)out;

    if (d) {
        const char4* p4 = (const char4*)((d - 1) ? xpk1 : xpk0);
        for (int i = tid; i < N / 4; i += 512) {
            char4 c = p4[i];
            o4[i] = make_float4((float)c.x, (float)c.y, (float)c.z, (float)c.w);
        }
        return;
    }
    const char4*  xp4 = (const char4*)xpk1;      // x_127
    const float4* y4  = (const float4*)y127;
    const float4* b4  = (const float4*)bias;
    float ep = 0.f;
    for (int i = tid; i < N / 4; i += 512) {
        char4 c = xp4[i];
        float4 y = y4[i], b = b4[i];
        ep += (((float)c.x * (-0.5f * y.x - b.x) + (float)c.y * (-0.5f * y.y - b.y)) +
               ((float)c.z * (-0.5f * y.z - b.z) + (float)c.w * (-0.5f * y.w - b.w)));
    }
    red[tid] = ep;
    __syncthreads();
    #pragma unroll
    for (int s = 256; s > 0; s >>= 1) {
        if (tid < s) red[tid] += red[tid + s];
        __syncthreads();
    }
    const bool conv = fabsf(red[0] - eacc[126]) < EPS;  // k=127 check
    for (int i = tid; i < N / 4; i += 512) {
        char4 c = xp4[i];
        float4 y = y4[i], b = b4[i];
        float4 r;
        r.x = conv ? (float)c.x : sgnf(y.x + b.x);
        r.y = conv ? (float)c.y : sgnf(y.y + b.y);
        r.z = conv ? (float)c.z : sgnf(y.z + b.z);
        r.w = conv ? (float)c.w : sgnf(y.w + b.w);
        o4[i] = r;
    }
}

// ===========================================================================
// Fallback (ws too small): the validated R3 full-fp32 chain.
// ===========================================================================
__global__ __launch_bounds__(256) void fb_init(float* __restrict__ eacc,
                                               int* __restrict__ done) {
    int i = threadIdx.x;
    if (i <= MAX_ITER) eacc[i] = 0.0f;
    if (i == 0) *done = 0;
}

__global__ __launch_bounds__(512, 4) void fb_mv(const float* __restrict__ W,
                                                const float* __restrict__ bias,
                                                const float* __restrict__ x0,
                                                const signed char* __restrict__ xin,
                                                signed char* __restrict__ xnext,
                                                float* __restrict__ eacc,
                                                int t,
                                                int* __restrict__ done) {
    if (t >= 2) {
        if (*done) return;
        float d = fabsf(eacc[t - 1] - eacc[t - 2]);
        if (d < EPS) {
            if (threadIdx.x == 0) *done = 1 + ((t - 1) & 1);
            return;
        }
    }
    __shared__ float xs[N];
    __shared__ float wsum[8];
    if (t == 0) {
        const float4* x4 = (const float4*)x0;
        float4* s4 = (float4*)xs;
        for (int i = threadIdx.x; i < N / 4; i += 512) s4[i] = x4[i];
    } else {
        #pragma unroll
        for (int k = 0; k < 16; ++k) {
            int e = threadIdx.x + k * 512;
            xs[e] = (float)xin[e];
        }
    }
    __syncthreads();
    const int wave = threadIdx.x >> 6;
    const int lane = threadIdx.x & 63;
    const int row  = ((int)blockIdx.x << 3) + wave;
    const float4* Wr  = (const float4*)(W + (size_t)row * N);
    const float4* xs4 = (const float4*)xs;
    float a0 = 0.f, a1 = 0.f, a2 = 0.f, a3 = 0.f;
    #pragma unroll
    for (int p = 0; p < 8; ++p) {
        int j = p * 256 + lane;
        float4 w0 = Wr[j];         float4 q0 = xs4[j];
        float4 w1 = Wr[j + 64];    float4 q1 = xs4[j + 64];
        float4 w2 = Wr[j + 128];   float4 q2 = xs4[j + 128];
        float4 w3 = Wr[j + 192];   float4 q3 = xs4[j + 192];
        a0 += w0.x * q0.x + w0.y * q0.y + w0.z * q0.z + w0.w * q0.w;
        a1 += w1.x * q1.x + w1.y * q1.y + w1.z * q1.z + w1.w * q1.w;
        a2 += w2.x * q2.x + w2.y * q2.y + w2.z * q2.z + w2.w * q2.w;
        a3 += w3.x * q3.x + w3.y * q3.y + w3.z * q3.z + w3.w * q3.w;
    }
    float tot = (a0 + a1) + (a2 + a3);
    #pragma unroll
    for (int off = 32; off > 0; off >>= 1) tot += __shfl_down(tot, off);
    if (lane == 0) {
        float br = bias[row];
        float v = tot + br;
        xnext[row] = (signed char)((v > 0.f) ? 1 : ((v < 0.f) ? -1 : 0));
        float xr = xs[row];
        wsum[wave] = -0.5f * xr * tot - br * xr;
    }
    __syncthreads();
    if (threadIdx.x == 0) {
        float s = 0.f;
        #pragma unroll
        for (int w = 0; w < 8; ++w) s += wsum[w];
        atomicAdd(&eacc[t], s);
    }
}

__global__ __launch_bounds__(256) void fb_out(const signed char* __restrict__ p0,
                                              const signed char* __restrict__ p1,
                                              const int* __restrict__ done,
                                              float* __restrict__ out) {
    int i = blockIdx.x * 256 + threadIdx.x;
    int d = *done;
    const signed char* p = d ? ((d - 1) ? p1 : p0) : p0;
    out[i] = (float)p[i];
}

// ===========================================================================
extern "C" void kernel_launch(void* const* d_in, const int* in_sizes, int n_in,
                              void* d_out, int out_size, void* d_ws, size_t ws_size,
                              hipStream_t stream) {
    const float* x0 = (const float*)d_in[0];   // (8192,)
    const float* W  = (const float*)d_in[1];   // (8192, 8192) fp32
    const float* b  = (const float*)d_in[2];   // (8192,)
    float* out = (float*)d_out;

    // fast-path workspace layout
    char* p = (char*)d_ws;
    signed char* Wq = (signed char*)p;        p += (size_t)N * N;      // 64 MiB
    float* yv   = (float*)p;                  p += 2 * N * sizeof(float);
    signed char* xpk = (signed char*)p;       p += 2 * N;
    float* eacc = (float*)p;                  p += MAX_ITER * sizeof(float);
    int*   cnt  = (int*)p;                    p += MAX_ITER * sizeof(int);
    int*   rows = (int*)p;                    p += MAX_ITER * LISTCAP * sizeof(int);
    int*   satflag = (int*)p;                 p += N * sizeof(int);
    int*   done = (int*)p;                    p += 16;
    const size_t needed = (size_t)(p - (char*)d_ws);

    if (ws_size >= needed) {
        init_kernel<<<N / 256, 256, 0, stream>>>(eacc, cnt, done, satflag);
        compress_kernel<<<(int)((size_t)N * N / (256 * 16)), 256, 0, stream>>>(W, Wq, satflag);
        for (int t = 0; t < MAX_ITER; ++t) {
            const float* yin = yv + ((t + 1) & 1) * N;          // y_{t-1}
            float*      yout = yv + (t & 1) * N;                // y_t
            const signed char* xprev = xpk + ((t + 1) & 1) * N; // x_{t-1}
            signed char*       xout  = xpk + (t & 1) * N;       // x_t
            passA<<<N / 8, 512, 0, stream>>>(Wq, b, x0, yin, yout, xprev, xout,
                                             eacc, cnt, rows, satflag, t, done);
            passB<<<128, 512, 0, stream>>>(W, x0, xout, yout, cnt, rows, t, done);
        }
        out_kernel<<<1, 512, 0, stream>>>(b, xpk, xpk + N, yv + N, eacc, done, out);
    } else {
        // fallback: validated R3 chain
        float*       feacc = (float*)d_ws;
        int*         fdone = (int*)(feacc + MAX_ITER + 2);
        signed char* p0    = (signed char*)(fdone + 16);
        signed char* p1    = p0 + N;
        fb_init<<<1, 256, 0, stream>>>(feacc, fdone);
        for (int t = 0; t <= MAX_ITER; ++t) {
            const signed char* xin   = (t & 1) ? p1 : p0;
            signed char*       xnext = (t & 1) ? p0 : p1;
            fb_mv<<<N / 8, 512, 0, stream>>>(W, b, x0, xin, xnext, feacc, t, fdone);
        }
        fb_out<<<N / 256, 256, 0, stream>>>(p0, p1, fdone, out);
    }
}